// Round 1
// baseline (2014.372 us; speedup 1.0000x reference)
//
#include <hip/hip_runtime.h>

// Elman RNN, B=256,T=256,I=128,H=512,O=1.
// Design: 16 blocks (one per 16-row batch group), 512 threads = 8 waves.
// Each wave owns 64 h-columns (4 MFMA n-tiles). Per step:
//   pre[16,512] = [h_t | x_t] (16x640, bf16, LDS) @ Bpack (640x512, bf16, global)
// Bpack = [W_hh^T ; W_ih^T] pre-packed in MFMA B-fragment order so the K-loop
// B-loads are coalesced global_load_dwordx4 straight into VGPRs (no LDS stage).
// W_ih fragments (K=128 tail) are loaded once and held in registers.
// h update: tanh in fp32, stored bf16 back into the LDS A-buffer. No inter-block
// communication at any point (sync-free across blocks; only __syncthreads).

#define B_   256
#define T_   256
#define I_   128
#define H_   512
#define NKC   20   // total K chunks of 32 (512 h + 128 x)
#define NKC_H 16   // K chunks covering W_hh
#define RS   648   // LDS row stride in bf16 elems: 640 + 8 pad (1296 B, 16B-mult)

typedef __attribute__((ext_vector_type(8))) short short8;
typedef __attribute__((ext_vector_type(4))) float f32x4;

static __device__ inline unsigned short f2bf(float f) {
    union { float f; unsigned u; } v; v.f = f;
    unsigned r = v.u + 0x7fffu + ((v.u >> 16) & 1u);   // RNE
    return (unsigned short)(r >> 16);
}
static __device__ inline float bf2f(unsigned short s) {
    union { unsigned u; float f; } v; v.u = ((unsigned)s) << 16;
    return v.f;
}
static __device__ inline float fast_tanh(float x) {
    // tanh(x) = 1 - 2/(exp(2x)+1); saturates correctly at +-inf
    float e = __expf(2.0f * x);
    return 1.0f - 2.0f / (e + 1.0f);
}

// Bpack[( (nt*NKC + kc)*64 + lane )*8 + e] = B[k][n] as bf16
//   k = kc*32 + (lane>>4)*8 + e,  n = nt*16 + (lane&15)
//   B[k][n] = (k < H) ? W_hh[n*H + k] : W_ih[n*I + (k-H)]
__global__ void pack_w(const float* __restrict__ W_ih,
                       const float* __restrict__ W_hh,
                       unsigned short* __restrict__ Bpack) {
    int idx = blockIdx.x * blockDim.x + threadIdx.x;   // one per (nt,kc,lane)
    if (idx >= 32 * NKC * 64) return;
    int lane = idx & 63;
    int kc   = (idx >> 6) % NKC;
    int nt   = (idx >> 6) / NKC;
    int n  = nt * 16 + (lane & 15);
    int k0 = kc * 32 + (lane >> 4) * 8;
    unsigned short* dst = Bpack + (size_t)idx * 8;
#pragma unroll
    for (int e = 0; e < 8; ++e) {
        int k = k0 + e;
        float v = (k < H_) ? W_hh[n * H_ + k] : W_ih[n * I_ + (k - H_)];
        dst[e] = f2bf(v);
    }
}

__global__ __launch_bounds__(512)
void rnn_main(const float* __restrict__ x,
              const unsigned short* __restrict__ Bpack,
              const float* __restrict__ b_ih,
              const float* __restrict__ b_hh,
              const float* __restrict__ fc_w,
              const float* __restrict__ fc_b,
              float* __restrict__ out) {
    __shared__ __align__(16) unsigned short a_lds[16 * RS];  // [m][k], k<512 = h, k>=512 = x_t

    const int tid  = threadIdx.x;
    const int lane = tid & 63;
    const int w    = tid >> 6;      // wave 0..7, owns cols [64w, 64w+64)
    const int q    = lane >> 4;     // 0..3
    const int mr   = lane & 15;
    const int bb   = blockIdx.x * 16;

    // zero LDS (h0 = 0)
    for (int i = tid; i < 16 * RS; i += 512) a_lds[i] = 0;

    // bias per owned n-tile (constant over t)
    float bias[4];
#pragma unroll
    for (int j = 0; j < 4; ++j) {
        int col = (4 * w + j) * 16 + mr;
        bias[j] = b_ih[col] + b_hh[col];
    }

    // register-resident W_ih B-fragments: [j][kx]
    short8 wih[4][4];
#pragma unroll
    for (int j = 0; j < 4; ++j)
#pragma unroll
        for (int kx = 0; kx < 4; ++kx) {
            int nt = 4 * w + j;
            wih[j][kx] = *(const short8*)(Bpack +
                ((size_t)(nt * NKC + NKC_H + kx) * 64 + lane) * 8);
        }

    // x staging: thread -> (row = tid>>5, 4 consecutive floats at col 4*(tid&31))
    const int xrow = tid >> 5;
    const int xc   = (tid & 31) * 4;
    const float* xbase = x + (size_t)(bb + xrow) * T_ * I_ + xc;
    float4 xreg = *(const float4*)(xbase);   // t = 0

    __syncthreads();  // LDS zeros visible

    f32x4 acc[4];
    for (int t = 0; t < T_; ++t) {
        // stage x_t into LDS (bf16)
        {
            ushort4 xs;
            xs.x = f2bf(xreg.x); xs.y = f2bf(xreg.y);
            xs.z = f2bf(xreg.z); xs.w = f2bf(xreg.w);
            *(ushort4*)&a_lds[xrow * RS + H_ + xc] = xs;
        }
        __syncthreads();   // x_t + h_t (prev epilogue) visible to everyone

        if (t + 1 < T_)
            xreg = *(const float4*)(xbase + (size_t)(t + 1) * I_);

#pragma unroll
        for (int j = 0; j < 4; ++j) acc[j] = (f32x4)(0.0f);

        // K loop over h part: B-frags streamed from global (packed layout)
        for (int kc = 0; kc < NKC_H; ++kc) {
            short8 af = *(const short8*)&a_lds[mr * RS + kc * 32 + q * 8];
#pragma unroll
            for (int j = 0; j < 4; ++j) {
                short8 bfr = *(const short8*)(Bpack +
                    ((size_t)((4 * w + j) * NKC + kc) * 64 + lane) * 8);
                acc[j] = __builtin_amdgcn_mfma_f32_16x16x32_bf16(af, bfr, acc[j], 0, 0, 0);
            }
        }
        // K loop over x part: B-frags from registers
#pragma unroll
        for (int kx = 0; kx < 4; ++kx) {
            short8 af = *(const short8*)&a_lds[mr * RS + H_ + kx * 32 + q * 8];
#pragma unroll
            for (int j = 0; j < 4; ++j)
                acc[j] = __builtin_amdgcn_mfma_f32_16x16x32_bf16(af, wih[j][kx], acc[j], 0, 0, 0);
        }
        __syncthreads();   // all reads of h_t / x_t done

        // epilogue: h_{t+1} = tanh(acc + bias) -> LDS h region
        // D layout: row m = q*4 + e, col n = (4w+j)*16 + mr
#pragma unroll
        for (int j = 0; j < 4; ++j) {
            int col = (4 * w + j) * 16 + mr;
#pragma unroll
            for (int e = 0; e < 4; ++e) {
                float hv = fast_tanh(acc[j][e] + bias[j]);
                a_lds[(q * 4 + e) * RS + col] = f2bf(hv);
            }
        }
    }
    __syncthreads();

    // out[b] = sum_n h_T[b][n] * fc_w[n] + fc_b  (32 threads per batch row)
    {
        const int row = tid >> 5;
        const int l32 = tid & 31;
        float s = 0.0f;
        for (int k = l32; k < H_; k += 32)
            s += bf2f(a_lds[row * RS + k]) * fc_w[k];
#pragma unroll
        for (int off = 16; off > 0; off >>= 1)
            s += __shfl_down(s, off, 32);
        if (l32 == 0) out[bb + row] = s + fc_b[0];
    }
}

extern "C" void kernel_launch(void* const* d_in, const int* in_sizes, int n_in,
                              void* d_out, int out_size, void* d_ws, size_t ws_size,
                              hipStream_t stream) {
    const float* x    = (const float*)d_in[0];
    const float* W_ih = (const float*)d_in[1];
    const float* W_hh = (const float*)d_in[2];
    const float* b_ih = (const float*)d_in[3];
    const float* b_hh = (const float*)d_in[4];
    const float* fc_w = (const float*)d_in[5];
    const float* fc_b = (const float*)d_in[6];
    unsigned short* Bpack = (unsigned short*)d_ws;   // 640*512*2 = 640 KB

    pack_w<<<160, 256, 0, stream>>>(W_ih, W_hh, Bpack);
    rnn_main<<<16, 512, 0, stream>>>(x, Bpack, b_ih, b_hh, fc_w, fc_b, (float*)d_out);
}

// Round 2
// 1213.971 us; speedup vs baseline: 1.6593x; 1.6593x over previous
//
#include <hip/hip_runtime.h>

// Elman RNN, B=256,T=256,I=128,H=512,O=1.
// 16 blocks (one per 16-row batch group), 512 threads = 8 waves, 1 block/CU.
// Each wave owns 64 h-columns (4 MFMA n-tiles).
// W (640x512, packed in MFMA B-fragment order in d_ws) is split:
//   kc 0..3   (128 KB)  -> LDS, preloaded once
//   kc 4..8   + W_ih    -> VGPR-resident fragments (144 VGPRs/wave)
//   kc 9..15  (224 KB)  -> streamed from L2 each step, 3-chunk rolling prefetch
// h update: fp32 tanh, stored bf16 into the LDS A-buffer. Sync-free across blocks.

#define B_   256
#define T_   256
#define I_   128
#define H_   512
#define NKC   20   // total K chunks of 32 (512 h + 128 x)
#define NKC_H 16   // K chunks covering W_hh
#define RS   648   // LDS A-row stride in bf16 elems (640 + 8 pad)

#define KC_LDS 4   // kc 0..3 in LDS
#define KC_REG 5   // kc 4..8 in regs
#define KC_STR 7   // kc 9..15 streamed

typedef __attribute__((ext_vector_type(8))) short short8;
typedef __attribute__((ext_vector_type(4))) float f32x4;

static __device__ inline unsigned short f2bf(float f) {
    union { float f; unsigned u; } v; v.f = f;
    unsigned r = v.u + 0x7fffu + ((v.u >> 16) & 1u);   // RNE
    return (unsigned short)(r >> 16);
}
static __device__ inline float bf2f(unsigned short s) {
    union { unsigned u; float f; } v; v.u = ((unsigned)s) << 16;
    return v.f;
}
static __device__ inline float fast_tanh(float x) {
    float e = __expf(2.0f * x);
    return 1.0f - 2.0f / (e + 1.0f);
}

// Bpack[( (nt*NKC + kc)*64 + lane )*8 + e] = B[k][n] as bf16
//   k = kc*32 + (lane>>4)*8 + e,  n = nt*16 + (lane&15)
//   B[k][n] = (k < H) ? W_hh[n*H + k] : W_ih[n*I + (k-H)]
__global__ void pack_w(const float* __restrict__ W_ih,
                       const float* __restrict__ W_hh,
                       unsigned short* __restrict__ Bpack) {
    int idx = blockIdx.x * blockDim.x + threadIdx.x;
    if (idx >= 32 * NKC * 64) return;
    int lane = idx & 63;
    int kc   = (idx >> 6) % NKC;
    int nt   = (idx >> 6) / NKC;
    int n  = nt * 16 + (lane & 15);
    int k0 = kc * 32 + (lane >> 4) * 8;
    unsigned short* dst = Bpack + (size_t)idx * 8;
#pragma unroll
    for (int e = 0; e < 8; ++e) {
        int k = k0 + e;
        float v = (k < H_) ? W_hh[n * H_ + k] : W_ih[n * I_ + (k - H_)];
        dst[e] = f2bf(v);
    }
}

__global__ __launch_bounds__(512, 2)
void rnn_main(const float* __restrict__ x,
              const unsigned short* __restrict__ Bpack,
              const float* __restrict__ b_ih,
              const float* __restrict__ b_hh,
              const float* __restrict__ fc_w,
              const float* __restrict__ fc_b,
              float* __restrict__ out) {
    __shared__ __align__(16) unsigned short a_lds[16 * RS];            // 20.25 KB
    __shared__ __align__(16) unsigned short w_lds[32 * KC_LDS * 64 * 8]; // 128 KB

    const int tid  = threadIdx.x;
    const int lane = tid & 63;
    const int w    = tid >> 6;      // wave 0..7, owns cols [64w, 64w+64)
    const int q    = lane >> 4;     // 0..3
    const int mr   = lane & 15;
    const int bb   = blockIdx.x * 16;

    // zero A-tile (h0 = 0)
    for (int i = tid; i < 16 * RS; i += 512) a_lds[i] = 0;

    // preload LDS-resident W chunks (kc 0..3), same fragment layout
    for (int i = tid; i < 32 * KC_LDS * 64; i += 512) {
        int l  = i & 63;
        int kc = (i >> 6) & (KC_LDS - 1);
        int nt = i >> 8;
        *(short8*)&w_lds[(size_t)i * 8] =
            *(const short8*)(Bpack + ((size_t)(nt * NKC + kc) * 64 + l) * 8);
    }

    // bias per owned n-tile
    float bias[4];
#pragma unroll
    for (int j = 0; j < 4; ++j) {
        int col = (4 * w + j) * 16 + mr;
        bias[j] = b_ih[col] + b_hh[col];
    }

    // register-resident fragments: W_ih (kc 16..19) and W_hh kc 4..8
    short8 wih[4][4];
#pragma unroll
    for (int j = 0; j < 4; ++j)
#pragma unroll
        for (int kx = 0; kx < 4; ++kx)
            wih[j][kx] = *(const short8*)(Bpack +
                ((size_t)((4 * w + j) * NKC + NKC_H + kx) * 64 + lane) * 8);

    short8 wreg[KC_REG][4];
#pragma unroll
    for (int r = 0; r < KC_REG; ++r)
#pragma unroll
        for (int j = 0; j < 4; ++j)
            wreg[r][j] = *(const short8*)(Bpack +
                ((size_t)((4 * w + j) * NKC + KC_LDS + r) * 64 + lane) * 8);

    // x staging: thread -> (row = tid>>5, 4 floats at col 4*(tid&31))
    const int xrow = tid >> 5;
    const int xc   = (tid & 31) * 4;
    const float* xbase = x + (size_t)(bb + xrow) * T_ * I_ + xc;
    float4 xreg = *(const float4*)(xbase);   // t = 0

    __syncthreads();  // a_lds zeros + w_lds visible

    f32x4 acc[4];
    short8 sb[3][4];   // streamed prefetch buffers (3 kc in flight)

    for (int t = 0; t < T_; ++t) {
        // issue streamed prefetch for kc 9,10,11 (overlaps barrier + no-load kcs)
#pragma unroll
        for (int s = 0; s < 3; ++s)
#pragma unroll
            for (int j = 0; j < 4; ++j)
                sb[s][j] = *(const short8*)(Bpack +
                    ((size_t)((4 * w + j) * NKC + KC_LDS + KC_REG + s) * 64 + lane) * 8);

        // stage x_t into LDS (bf16)
        {
            ushort4 xs;
            xs.x = f2bf(xreg.x); xs.y = f2bf(xreg.y);
            xs.z = f2bf(xreg.z); xs.w = f2bf(xreg.w);
            *(ushort4*)&a_lds[xrow * RS + H_ + xc] = xs;
        }
        __syncthreads();   // x_t + h_t visible

        if (t + 1 < T_)
            xreg = *(const float4*)(xbase + (size_t)(t + 1) * I_);

#pragma unroll
        for (int j = 0; j < 4; ++j) acc[j] = (f32x4)(0.0f);

        // --- LDS-resident kcs (0..3) ---
#pragma unroll
        for (int kc = 0; kc < KC_LDS; ++kc) {
            short8 af = *(const short8*)&a_lds[mr * RS + kc * 32 + q * 8];
#pragma unroll
            for (int j = 0; j < 4; ++j) {
                short8 bfr = *(const short8*)&w_lds[
                    (size_t)(((4 * w + j) * KC_LDS + kc) * 64 + lane) * 8];
                acc[j] = __builtin_amdgcn_mfma_f32_16x16x32_bf16(af, bfr, acc[j], 0, 0, 0);
            }
        }
        // --- register-resident W_hh kcs (4..8) ---
#pragma unroll
        for (int r = 0; r < KC_REG; ++r) {
            short8 af = *(const short8*)&a_lds[mr * RS + (KC_LDS + r) * 32 + q * 8];
#pragma unroll
            for (int j = 0; j < 4; ++j)
                acc[j] = __builtin_amdgcn_mfma_f32_16x16x32_bf16(af, wreg[r][j], acc[j], 0, 0, 0);
        }
        // --- register-resident W_ih (x part, kc 16..19) ---
#pragma unroll
        for (int kx = 0; kx < 4; ++kx) {
            short8 af = *(const short8*)&a_lds[mr * RS + H_ + kx * 32 + q * 8];
#pragma unroll
            for (int j = 0; j < 4; ++j)
                acc[j] = __builtin_amdgcn_mfma_f32_16x16x32_bf16(af, wih[j][kx], acc[j], 0, 0, 0);
        }
        // --- streamed kcs (9..15), rolling 3-deep prefetch ---
#pragma unroll
        for (int s = 0; s < KC_STR; ++s) {
            int kc = KC_LDS + KC_REG + s;
            short8 af = *(const short8*)&a_lds[mr * RS + kc * 32 + q * 8];
#pragma unroll
            for (int j = 0; j < 4; ++j)
                acc[j] = __builtin_amdgcn_mfma_f32_16x16x32_bf16(af, sb[s % 3][j], acc[j], 0, 0, 0);
            if (s + 3 < KC_STR) {
#pragma unroll
                for (int j = 0; j < 4; ++j)
                    sb[s % 3][j] = *(const short8*)(Bpack +
                        ((size_t)((4 * w + j) * NKC + kc + 3) * 64 + lane) * 8);
            }
        }
        __syncthreads();   // all A-reads done

        // epilogue: h_{t+1} = tanh(acc + bias); D row m = q*4+e, col = (4w+j)*16+mr
#pragma unroll
        for (int j = 0; j < 4; ++j) {
            int col = (4 * w + j) * 16 + mr;
#pragma unroll
            for (int e = 0; e < 4; ++e) {
                float hv = fast_tanh(acc[j][e] + bias[j]);
                a_lds[(q * 4 + e) * RS + col] = f2bf(hv);
            }
        }
    }
    __syncthreads();

    // out[b] = h_T[b] . fc_w + fc_b  (32 threads per batch row)
    {
        const int row = tid >> 5;
        const int l32 = tid & 31;
        float s = 0.0f;
        for (int k = l32; k < H_; k += 32)
            s += bf2f(a_lds[row * RS + k]) * fc_w[k];
#pragma unroll
        for (int off = 16; off > 0; off >>= 1)
            s += __shfl_down(s, off, 32);
        if (l32 == 0) out[bb + row] = s + fc_b[0];
    }
}

extern "C" void kernel_launch(void* const* d_in, const int* in_sizes, int n_in,
                              void* d_out, int out_size, void* d_ws, size_t ws_size,
                              hipStream_t stream) {
    const float* x    = (const float*)d_in[0];
    const float* W_ih = (const float*)d_in[1];
    const float* W_hh = (const float*)d_in[2];
    const float* b_ih = (const float*)d_in[3];
    const float* b_hh = (const float*)d_in[4];
    const float* fc_w = (const float*)d_in[5];
    const float* fc_b = (const float*)d_in[6];
    unsigned short* Bpack = (unsigned short*)d_ws;   // 640*512*2 = 640 KB

    pack_w<<<160, 256, 0, stream>>>(W_ih, W_hh, Bpack);
    rnn_main<<<16, 512, 0, stream>>>(x, Bpack, b_ih, b_hh, fc_w, fc_b, (float*)d_out);
}